// Round 3
// baseline (824.962 us; speedup 1.0000x reference)
//
#include <hip/hip_runtime.h>
#include <hip/hip_bf16.h>
#include <cstdint>

// Problem constants: B=64, T=512, E=256, H=128, 4H=512.
#define BB 64
#define TT 512
#define EE 256
#define HH 128
#define G4 512

typedef _Float16 half2_t __attribute__((ext_vector_type(2)));
typedef _Float16 f16x4 __attribute__((ext_vector_type(4)));
typedef _Float16 f16x8 __attribute__((ext_vector_type(8)));
typedef float f32x4 __attribute__((ext_vector_type(4)));

#define BC(x) __builtin_bit_cast(half2_t, x)

__device__ __forceinline__ float fdot2f(half2_t a, half2_t b, float c) {
#if defined(__has_builtin)
#if __has_builtin(__builtin_amdgcn_fdot2)
  return __builtin_amdgcn_fdot2(a, b, c, false);
#else
  return c + (float)a[0] * (float)b[0] + (float)a[1] * (float)b[1];
#endif
#else
  return c + (float)a[0] * (float)b[0] + (float)a[1] * (float)b[1];
#endif
}

__device__ __forceinline__ float rcp_(float x) { return __builtin_amdgcn_rcpf(x); }
__device__ __forceinline__ float sigmoid_(float x) {
  return rcp_(1.f + __expf(-x));
}
__device__ __forceinline__ float tanh_(float x) {
  float ax = fabsf(x);
  float e = __expf(-2.f * ax);             // in (0,1], no overflow ever
  float r = (1.f - e) * rcp_(1.f + e);
  return copysignf(r, x);
}

// ---------------------------------------------------------------------------
// Kernel A: trans = row-softmax(transition); W16 = (f16)W_ih
// grid 256 x 128 threads. blocks 0..127: softmax row; 128..255: W_ih convert.
// ---------------------------------------------------------------------------
__global__ __launch_bounds__(128) void prep_kernel(
    const float* __restrict__ transition, const float* __restrict__ W_ih,
    float* __restrict__ trans, _Float16* __restrict__ W16) {
  const int bid = blockIdx.x, t = threadIdx.x;
  if (bid < 128) {
    __shared__ float red[2];
    float v = transition[bid * HH + t];
    float m = v;
#pragma unroll
    for (int s = 32; s >= 1; s >>= 1) m = fmaxf(m, __shfl_xor(m, s));
    if ((t & 63) == 0) red[t >> 6] = m;
    __syncthreads();
    m = fmaxf(red[0], red[1]);
    float e = __expf(v - m);
    float s = e;
#pragma unroll
    for (int k = 32; k >= 1; k >>= 1) s += __shfl_xor(s, k);
    __syncthreads();  // protect red before reuse
    if ((t & 63) == 0) red[t >> 6] = s;
    __syncthreads();
    trans[bid * HH + t] = e * rcp_(red[0] + red[1]);
  } else {
    const int base = (bid - 128) * 1024 + t * 8;  // 131072 total elems
    float4 v0 = *(const float4*)(W_ih + base);
    float4 v1 = *(const float4*)(W_ih + base + 4);
    f16x8 h;
    h[0] = (_Float16)v0.x; h[1] = (_Float16)v0.y;
    h[2] = (_Float16)v0.z; h[3] = (_Float16)v0.w;
    h[4] = (_Float16)v1.x; h[5] = (_Float16)v1.y;
    h[6] = (_Float16)v1.z; h[7] = (_Float16)v1.w;
    *(f16x8*)(W16 + base) = h;
  }
}

// ---------------------------------------------------------------------------
// Kernel B: precomp[m][j] = sum_e inputs[m][e]*W_ih[j][e] + b_ih[j] + b_hh[j]
// M=32768, N=512, K=256.  MFMA f16 16x16x32.  grid (512, 2) x 256 threads.
// ---------------------------------------------------------------------------
__global__ __launch_bounds__(256) void gemm_in(
    const float* __restrict__ A, const _Float16* __restrict__ W16,
    const float* __restrict__ b_ih, const float* __restrict__ b_hh,
    float* __restrict__ out) {
  __shared__ _Float16 As[64][264];  // K=256 + 8 pad (16B-aligned rows)
  const int t = threadIdx.x;
  const int m0 = blockIdx.x * 64;
  const int n0 = blockIdx.y * 256;
  {
    const int c4 = t & 63, r0 = t >> 6;
#pragma unroll
    for (int p = 0; p < 16; ++p) {
      const int row = r0 + 4 * p;
      float4 v = *(const float4*)(A + (size_t)(m0 + row) * EE + c4 * 4);
      f16x4 h;
      h[0] = (_Float16)v.x; h[1] = (_Float16)v.y;
      h[2] = (_Float16)v.z; h[3] = (_Float16)v.w;
      *(f16x4*)&As[row][c4 * 4] = h;
    }
  }
  __syncthreads();
  const int w = t >> 6, L = t & 63;
  const int lrow = L & 15, quad = L >> 4, lk = quad * 8;
  f32x4 acc[4][4] = {};
  const _Float16* Wbase = W16 + (size_t)(n0 + w * 64) * EE;
#pragma unroll
  for (int kc = 0; kc < 8; ++kc) {
    f16x8 a[4], bf[4];
#pragma unroll
    for (int mf = 0; mf < 4; ++mf)
      a[mf] = *(const f16x8*)&As[mf * 16 + lrow][kc * 32 + lk];
#pragma unroll
    for (int nf = 0; nf < 4; ++nf)
      bf[nf] = *(const f16x8*)(Wbase + (size_t)(nf * 16 + lrow) * EE + kc * 32 + lk);
#pragma unroll
    for (int mf = 0; mf < 4; ++mf)
#pragma unroll
      for (int nf = 0; nf < 4; ++nf)
        acc[mf][nf] = __builtin_amdgcn_mfma_f32_16x16x32_f16(a[mf], bf[nf], acc[mf][nf], 0, 0, 0);
  }
#pragma unroll
  for (int nf = 0; nf < 4; ++nf) {
    const int j = n0 + w * 64 + nf * 16 + lrow;  // C/D: col = lane&15
    const float bias = b_ih[j] + b_hh[j];
#pragma unroll
    for (int mf = 0; mf < 4; ++mf) {
#pragma unroll
      for (int r = 0; r < 4; ++r) {  // C/D: row = quad*4 + r
        const int m = m0 + mf * 16 + quad * 4 + r;
        out[(size_t)m * G4 + j] = acc[mf][nf][r] + bias;
      }
    }
  }
}

// ---------------------------------------------------------------------------
// Kernel C: fused LSTM recurrence + softmax + CRF forward.  One 512-thread
// block per batch.  K-SPLIT-4 layout: lane (qq=l>>4, r=l&15) of wave wv
// computes the K-quarter [32qq,32qq+32) partial dots for the 4 gate rows of
// unit u = wv*16+r AND the CRF column u; shfl_xor(16/32) butterflies finish
// the dots in-register.  LDS traffic/wave/step: 8 broadcast b128 reads + ws
// round-trip + 2 b16 writes (vs 22 instr before — LDS pipe was the
// bottleneck).  Activations one-per-lane (gate j==qq), gathered to owner
// lanes with 3 shfl_xor.  2 barriers/step; h_lds double-buffered.
// ---------------------------------------------------------------------------
__global__ __launch_bounds__(512, 2) void lstm_crf(
    const float* __restrict__ precomp, const float* __restrict__ Whh,
    const float* __restrict__ trans, const int* __restrict__ labels,
    float* __restrict__ out_b) {
  const int b = blockIdx.x, t = threadIdx.x;
  const int l = t & 63;
  const int wv = t >> 6;
  const int qq = l >> 4;
  const int r = l & 15;
  const int u = wv * 16 + r;   // unit owned (state lives on qq==0 lanes)

  __shared__ __align__(16) _Float16 h_lds[2][HH];
  __shared__ __align__(16) _Float16 E_lds[HH];
  __shared__ __align__(16) float ws[16];
  __shared__ int lab[TT];

  // --- one-time loads -------------------------------------------------------
  // W_hh rows {u, u+128, u+256, u+384}, cols [32qq, 32qq+32), as f16 pairs
  half2_t wreg[4][16];
#pragma unroll
  for (int j = 0; j < 4; ++j) {
    const float* row = Whh + (size_t)(j * HH + u) * HH + qq * 32;
#pragma unroll
    for (int f = 0; f < 8; ++f) {
      float4 v = *(const float4*)(row + 4 * f);
      half2_t p0, p1;
      p0[0] = (_Float16)v.x; p0[1] = (_Float16)v.y;
      p1[0] = (_Float16)v.z; p1[1] = (_Float16)v.w;
      wreg[j][2 * f] = p0; wreg[j][2 * f + 1] = p1;
    }
  }
  // et[a] = exp(trans[32qq+2a][u]), exp(trans[32qq+2a+1][u])  (K-slice, col u)
  half2_t et[16];
#pragma unroll
  for (int a = 0; a < 16; ++a) {
    float e0 = __expf(trans[(qq * 32 + 2 * a) * HH + u]);
    float e1 = __expf(trans[(qq * 32 + 2 * a + 1) * HH + u]);
    half2_t h2; h2[0] = (_Float16)e0; h2[1] = (_Float16)e1;
    et[a] = h2;
  }
  const float tr0 = trans[u];
  const float tr127 = trans[127 * HH + u];
  lab[t] = labels[b * TT + t];
  if (t < HH) { h_lds[0][t] = (_Float16)0.f; E_lds[t] = (_Float16)0.f; }

  float c = 0.f, pre = 0.f, mused = 0.f, emit = 0.f;
  const float* pcb = precomp + (size_t)b * TT * G4;
  float nx0 = pcb[u], nx1 = pcb[HH + u], nx2 = pcb[2 * HH + u], nx3 = pcb[3 * HH + u];
  __syncthreads();

#pragma unroll 1
  for (int step = 0; step < TT; ++step) {
    const int buf = step & 1;
    const float cu0 = nx0, cu1 = nx1, cu2 = nx2, cu3 = nx3;
    if (step < TT - 1) {
      const float* pn = pcb + (size_t)(step + 1) * G4;
      nx0 = pn[u]; nx1 = pn[HH + u]; nx2 = pn[2 * HH + u]; nx3 = pn[3 * HH + u];
    }
    // --- K-quarter chunks of h and E (4+4 broadcast b128 reads) ------------
    const float4* hq = (const float4*)&h_lds[buf][qq * 32];
    float4 hA = hq[0], hB = hq[1], hC = hq[2], hD = hq[3];
    const float4* eq = (const float4*)&E_lds[qq * 32];
    float4 eA = eq[0], eB = eq[1], eC = eq[2], eD = eq[3];
    half2_t hh[16], ee[16];
    hh[0] = BC(hA.x); hh[1] = BC(hA.y); hh[2] = BC(hA.z); hh[3] = BC(hA.w);
    hh[4] = BC(hB.x); hh[5] = BC(hB.y); hh[6] = BC(hB.z); hh[7] = BC(hB.w);
    hh[8] = BC(hC.x); hh[9] = BC(hC.y); hh[10] = BC(hC.z); hh[11] = BC(hC.w);
    hh[12] = BC(hD.x); hh[13] = BC(hD.y); hh[14] = BC(hD.z); hh[15] = BC(hD.w);
    ee[0] = BC(eA.x); ee[1] = BC(eA.y); ee[2] = BC(eA.z); ee[3] = BC(eA.w);
    ee[4] = BC(eB.x); ee[5] = BC(eB.y); ee[6] = BC(eB.z); ee[7] = BC(eB.w);
    ee[8] = BC(eC.x); ee[9] = BC(eC.y); ee[10] = BC(eC.z); ee[11] = BC(eC.w);
    ee[12] = BC(eD.x); ee[13] = BC(eD.y); ee[14] = BC(eD.z); ee[15] = BC(eD.w);
    // --- quarter dots: 4 gate rows + 1 CRF column --------------------------
    float d0 = 0.f, d1 = 0.f, d2 = 0.f, d3 = 0.f, sS = 0.f;
#pragma unroll
    for (int a = 0; a < 16; ++a) {
      d0 = fdot2f(wreg[0][a], hh[a], d0);
      d1 = fdot2f(wreg[1][a], hh[a], d1);
      d2 = fdot2f(wreg[2][a], hh[a], d2);
      d3 = fdot2f(wreg[3][a], hh[a], d3);
      sS = fdot2f(et[a], ee[a], sS);
    }
    // butterfly over K-quarters: every lane gets the full sums
    d0 += __shfl_xor(d0, 16); d0 += __shfl_xor(d0, 32);
    d1 += __shfl_xor(d1, 16); d1 += __shfl_xor(d1, 32);
    d2 += __shfl_xor(d2, 16); d2 += __shfl_xor(d2, 32);
    d3 += __shfl_xor(d3, 16); d3 += __shfl_xor(d3, 32);
    sS += __shfl_xor(sS, 16); sS += __shfl_xor(sS, 32);
    // --- own-gate activation (gate j == qq), branchless --------------------
    const float g0 = cu0 + d0, g1 = cu1 + d1, g2 = cu2 + d2, g3 = cu3 + d3;
    const float xg = (qq == 0) ? g0 : (qq == 1) ? g1 : (qq == 2) ? g2 : g3;
    const bool isg = (qq == 2);
    const float yy = isg ? (-2.f * fabsf(xg)) : (-xg);
    const float exv = __expf(yy);
    const float num = isg ? (1.f - exv) : 1.f;
    float aown = num * rcp_(1.f + exv);
    aown = isg ? copysignf(aown, xg) : aown;
    // gather i,f,g,o to qq==0 lanes (on q0: aown=i, a1=f, a2=g, a3=o)
    const float a1 = __shfl_xor(aown, 16);
    const float a2 = __shfl_xor(aown, 32);
    const float a3 = __shfl_xor(a1, 32);
    c = a1 * c + aown * a2;             // meaningful on q0; bounded elsewhere
    const float hval = a3 * tanh_(c);
    const float eh = __expf(hval);      // |hval|<1 on q0
    if (qq == 0) h_lds[buf ^ 1][u] = (_Float16)hval;
    // softmax denominator: wave partial (q0 lanes only) -> ws
    float ehm = (qq == 0) ? eh : 0.f;
    ehm += __shfl_xor(ehm, 1); ehm += __shfl_xor(ehm, 2);
    ehm += __shfl_xor(ehm, 4); ehm += __shfl_xor(ehm, 8);
    ehm += __shfl_xor(ehm, 16); ehm += __shfl_xor(ehm, 32);
    if (l == 0) ws[wv] = ehm;
    if (t == 0) ws[8] = sS;             // S[0] (unit 0)
    __syncthreads();  // B
    // --- finalize: p, CRF update, E write ----------------------------------
    const float4 w0 = *(const float4*)ws;
    const float4 w1 = *(const float4*)(ws + 4);
    const float S0 = ws[8];
    const int lb = lab[step];
    const float denom = ((w0.x + w0.y) + (w0.z + w0.w)) + ((w1.x + w1.y) + (w1.z + w1.w));
    const float p = eh * rcp_(denom);
    const float lgS = __logf(sS);
    const float Mnext = (step == 0) ? 0.f : (mused + __logf(S0));
    pre = p + ((step == 0) ? tr0 : (mused + lgS));
    if (qq == 0 && u == lb) emit += p;
    if (qq == 0) E_lds[u] = (_Float16)__expf(pre - Mnext);  // in [~0.37, ~7.4]
    mused = Mnext;
    __syncthreads();  // C
  }
  // --- epilogue: Ps = LSE_u(pre + trans[127][u]); out_b = Ps - emit --------
  float v = (qq == 0) ? (pre + tr127) : -3.0e38f;
#pragma unroll
  for (int s = 1; s <= 32; s <<= 1) v = fmaxf(v, __shfl_xor(v, s));
  if (l == 0) ws[wv] = v;
  __syncthreads();
  const float4 m0 = *(const float4*)ws;
  const float4 m1 = *(const float4*)(ws + 4);
  const float M2 = fmaxf(fmaxf(fmaxf(m0.x, m0.y), fmaxf(m0.z, m0.w)),
                         fmaxf(fmaxf(m1.x, m1.y), fmaxf(m1.z, m1.w)));
  float exs = (qq == 0) ? __expf(pre + tr127 - M2) : 0.f;
  float em = emit;
#pragma unroll
  for (int s = 1; s <= 32; s <<= 1) {
    exs += __shfl_xor(exs, s);
    em += __shfl_xor(em, s);
  }
  __syncthreads();  // all reads of ws done before rewrite
  if (l == 0) { ws[wv] = exs; ws[8 + wv] = em; }
  __syncthreads();
  if (t == 0) {
    float sx = 0.f, se = 0.f;
#pragma unroll
    for (int i = 0; i < 8; ++i) { sx += ws[i]; se += ws[8 + i]; }
    out_b[b] = M2 + __logf(sx) - se;
  }
}

// ---------------------------------------------------------------------------
// Kernel D: total = sum_b out_b[b] - sum_{b,t<511} trans[l_t][l_{t+1}]
// ---------------------------------------------------------------------------
__global__ __launch_bounds__(512) void finalize_kernel(
    const float* __restrict__ trans, const int* __restrict__ labels,
    const float* __restrict__ out_b, float* __restrict__ d_out) {
  const int t = threadIdx.x;
  float a = 0.f;
  if (t < TT - 1) {
    for (int b = 0; b < BB; ++b) {
      const int l0 = labels[b * TT + t];
      const int l1 = labels[b * TT + t + 1];
      a += trans[l0 * HH + l1];
    }
  }
  float x = ((t < BB) ? out_b[t] : 0.f) - a;
  __shared__ float red[8];
#pragma unroll
  for (int s = 32; s >= 1; s >>= 1) x += __shfl_xor(x, s);
  if ((t & 63) == 0) red[t >> 6] = x;
  __syncthreads();
  if (t == 0) {
    float s = 0.f;
#pragma unroll
    for (int i = 0; i < 8; ++i) s += red[i];
    d_out[0] = s;
  }
}

// ---------------------------------------------------------------------------
extern "C" void kernel_launch(void* const* d_in, const int* in_sizes, int n_in,
                              void* d_out, int out_size, void* d_ws, size_t ws_size,
                              hipStream_t stream) {
  const float* inputs = (const float*)d_in[0];      // (64,512,256) f32
  const int* labels = (const int*)d_in[1];          // (64,512) i32
  const float* W_ih = (const float*)d_in[2];        // (512,256) f32
  const float* W_hh = (const float*)d_in[3];        // (512,128) f32
  const float* b_ih = (const float*)d_in[4];        // (512,) f32
  const float* b_hh = (const float*)d_in[5];        // (512,) f32
  const float* transition = (const float*)d_in[6];  // (128,128) f32

  char* ws = (char*)d_ws;
  float* precomp = (float*)ws;                           // 64 MiB
  float* trans = (float*)(ws + 67108864);                // 64 KiB
  _Float16* W16 = (_Float16*)(ws + 67108864 + 65536);    // 256 KiB
  float* out_b = (float*)(ws + 67108864 + 65536 + 262144);

  prep_kernel<<<256, 128, 0, stream>>>(transition, W_ih, trans, W16);
  gemm_in<<<dim3(512, 2), 256, 0, stream>>>(inputs, W16, b_ih, b_hh, precomp);
  lstm_crf<<<64, 512, 0, stream>>>(precomp, W_hh, trans, labels, out_b);
  finalize_kernel<<<1, 512, 0, stream>>>(trans, labels, out_b, (float*)d_out);
}

// Round 4
// 605.452 us; speedup vs baseline: 1.3626x; 1.3626x over previous
//
#include <hip/hip_runtime.h>
#include <hip/hip_bf16.h>
#include <cstdint>

// Problem constants: B=64, T=512, E=256, H=128, 4H=512.
#define BB 64
#define TT 512
#define EE 256
#define HH 128
#define G4 512

typedef _Float16 half2_t __attribute__((ext_vector_type(2)));
typedef _Float16 f16x4 __attribute__((ext_vector_type(4)));
typedef _Float16 f16x8 __attribute__((ext_vector_type(8)));
typedef float f32x4 __attribute__((ext_vector_type(4)));

#define BC(x) __builtin_bit_cast(half2_t, x)

__device__ __forceinline__ float fdot2f(half2_t a, half2_t b, float c) {
#if defined(__has_builtin)
#if __has_builtin(__builtin_amdgcn_fdot2)
  return __builtin_amdgcn_fdot2(a, b, c, false);
#else
  return c + (float)a[0] * (float)b[0] + (float)a[1] * (float)b[1];
#endif
#else
  return c + (float)a[0] * (float)b[0] + (float)a[1] * (float)b[1];
#endif
}

__device__ __forceinline__ float rcp_(float x) { return __builtin_amdgcn_rcpf(x); }
__device__ __forceinline__ float tanh_(float x) {
  float ax = fabsf(x);
  float e = __expf(-2.f * ax);             // in (0,1], no overflow ever
  float r = (1.f - e) * rcp_(1.f + e);
  return copysignf(r, x);
}

__device__ __forceinline__ float readlane_f(float x, int lane) {
#if defined(__has_builtin)
#if __has_builtin(__builtin_amdgcn_readlane)
  return __builtin_bit_cast(float, __builtin_amdgcn_readlane(__builtin_bit_cast(int, x), lane));
#else
  return __shfl(x, lane);
#endif
#else
  return __shfl(x, lane);
#endif
}

// 64-lane sum via DPP (VALU pipe, not LDS pipe).  Result broadcast to all
// lanes via readlane(63).  row_shr:1/2/4/8 -> row sums in lane 15 of each
// row; row_bcast15 -> lane31 = rows0+1; row_bcast31 -> lane63 = total.
#if defined(__has_builtin)
#if __has_builtin(__builtin_amdgcn_update_dpp)
#define HAVE_DPP 1
#endif
#endif

__device__ __forceinline__ float wave_sum64_bcast(float x) {
#ifdef HAVE_DPP
#define DPP_ADD(ctrl)                                                          \
  {                                                                            \
    int _t = __builtin_amdgcn_update_dpp(0, __builtin_bit_cast(int, x), ctrl,  \
                                         0xf, 0xf, true);                      \
    x += __builtin_bit_cast(float, _t);                                        \
  }
  DPP_ADD(0x111)  // row_shr:1
  DPP_ADD(0x112)  // row_shr:2
  DPP_ADD(0x114)  // row_shr:4
  DPP_ADD(0x118)  // row_shr:8
  DPP_ADD(0x142)  // row_bcast:15
  DPP_ADD(0x143)  // row_bcast:31
#undef DPP_ADD
  return readlane_f(x, 63);
#else
#pragma unroll
  for (int s = 1; s <= 32; s <<= 1) x += __shfl_xor(x, s);
  return x;
#endif
}

// ---------------------------------------------------------------------------
// Kernel A: trans = row-softmax(transition); W16 = (f16)W_ih
// ---------------------------------------------------------------------------
__global__ __launch_bounds__(128) void prep_kernel(
    const float* __restrict__ transition, const float* __restrict__ W_ih,
    float* __restrict__ trans, _Float16* __restrict__ W16) {
  const int bid = blockIdx.x, t = threadIdx.x;
  if (bid < 128) {
    __shared__ float red[2];
    float v = transition[bid * HH + t];
    float m = v;
#pragma unroll
    for (int s = 32; s >= 1; s >>= 1) m = fmaxf(m, __shfl_xor(m, s));
    if ((t & 63) == 0) red[t >> 6] = m;
    __syncthreads();
    m = fmaxf(red[0], red[1]);
    float e = __expf(v - m);
    float s = e;
#pragma unroll
    for (int k = 32; k >= 1; k >>= 1) s += __shfl_xor(s, k);
    __syncthreads();  // protect red before reuse
    if ((t & 63) == 0) red[t >> 6] = s;
    __syncthreads();
    trans[bid * HH + t] = e * rcp_(red[0] + red[1]);
  } else {
    const int base = (bid - 128) * 1024 + t * 8;  // 131072 total elems
    float4 v0 = *(const float4*)(W_ih + base);
    float4 v1 = *(const float4*)(W_ih + base + 4);
    f16x8 h;
    h[0] = (_Float16)v0.x; h[1] = (_Float16)v0.y;
    h[2] = (_Float16)v0.z; h[3] = (_Float16)v0.w;
    h[4] = (_Float16)v1.x; h[5] = (_Float16)v1.y;
    h[6] = (_Float16)v1.z; h[7] = (_Float16)v1.w;
    *(f16x8*)(W16 + base) = h;
  }
}

// ---------------------------------------------------------------------------
// Kernel B: precomp[m][j] = sum_e inputs[m][e]*W_ih[j][e] + b_ih[j] + b_hh[j]
// M=32768, N=512, K=256.  MFMA f16 16x16x32.  grid (512, 2) x 256 threads.
// ---------------------------------------------------------------------------
__global__ __launch_bounds__(256) void gemm_in(
    const float* __restrict__ A, const _Float16* __restrict__ W16,
    const float* __restrict__ b_ih, const float* __restrict__ b_hh,
    float* __restrict__ out) {
  __shared__ _Float16 As[64][264];  // K=256 + 8 pad (16B-aligned rows)
  const int t = threadIdx.x;
  const int m0 = blockIdx.x * 64;
  const int n0 = blockIdx.y * 256;
  {
    const int c4 = t & 63, r0 = t >> 6;
#pragma unroll
    for (int p = 0; p < 16; ++p) {
      const int row = r0 + 4 * p;
      float4 v = *(const float4*)(A + (size_t)(m0 + row) * EE + c4 * 4);
      f16x4 h;
      h[0] = (_Float16)v.x; h[1] = (_Float16)v.y;
      h[2] = (_Float16)v.z; h[3] = (_Float16)v.w;
      *(f16x4*)&As[row][c4 * 4] = h;
    }
  }
  __syncthreads();
  const int w = t >> 6, L = t & 63;
  const int lrow = L & 15, quad = L >> 4, lk = quad * 8;
  f32x4 acc[4][4] = {};
  const _Float16* Wbase = W16 + (size_t)(n0 + w * 64) * EE;
#pragma unroll
  for (int kc = 0; kc < 8; ++kc) {
    f16x8 a[4], bf[4];
#pragma unroll
    for (int mf = 0; mf < 4; ++mf)
      a[mf] = *(const f16x8*)&As[mf * 16 + lrow][kc * 32 + lk];
#pragma unroll
    for (int nf = 0; nf < 4; ++nf)
      bf[nf] = *(const f16x8*)(Wbase + (size_t)(nf * 16 + lrow) * EE + kc * 32 + lk);
#pragma unroll
    for (int mf = 0; mf < 4; ++mf)
#pragma unroll
      for (int nf = 0; nf < 4; ++nf)
        acc[mf][nf] = __builtin_amdgcn_mfma_f32_16x16x32_f16(a[mf], bf[nf], acc[mf][nf], 0, 0, 0);
  }
#pragma unroll
  for (int nf = 0; nf < 4; ++nf) {
    const int j = n0 + w * 64 + nf * 16 + lrow;  // C/D: col = lane&15
    const float bias = b_ih[j] + b_hh[j];
#pragma unroll
    for (int mf = 0; mf < 4; ++mf) {
#pragma unroll
      for (int r = 0; r < 4; ++r) {  // C/D: row = quad*4 + r
        const int m = m0 + mf * 16 + quad * 4 + r;
        out[(size_t)m * G4 + j] = acc[mf][nf][r] + bias;
      }
    }
  }
}

// ---------------------------------------------------------------------------
// Kernel C: fused LSTM + softmax + CRF forward.  One 512-thread block/batch.
// Thread t = gate row (g = t>>7 in {i,f,g,o}, unit j = t&127).
// Per step (2 barriers):
//   phase 1 (all): gate = precomp + W_hh[t]·h (full K, 16 b128 broadcast
//     reads) -> act2[j*4+g]; CRF K-quarter dot -> Spart2[j*4+g].
//   phase 3 (wave 0 only, lane l owns units 2l,2l+1): 2+2 b128 reads give
//     all gates + S partials; cell update; softmax denom via DPP wave-sum
//     (VALU, not LDS pipe); CRF max-proxy recursion in registers; E/h f16
//     writes.  No cross-wave scalar round trips.
// Global precomp prefetched in batches of 8 steps (cbuf/nbuf, static idx):
// __syncthreads' implicit vmcnt(0) drain pays HBM latency once per 8 steps.
// ---------------------------------------------------------------------------
__global__ __launch_bounds__(512, 2) void lstm_crf(
    const float* __restrict__ precomp, const float* __restrict__ Whh,
    const float* __restrict__ trans, const int* __restrict__ labels,
    float* __restrict__ out_b) {
  const int b = blockIdx.x, t = threadIdx.x;
  const int g = t >> 7;    // gate index (i,f,g,o) and CRF K-quarter
  const int j = t & 127;   // unit index

  __shared__ __align__(16) _Float16 h_lds[HH];
  __shared__ __align__(16) _Float16 E_lds[HH];
  __shared__ __align__(16) float act2[G4];    // [unit][gate]
  __shared__ __align__(16) float Spart2[G4];  // [unit][quarter]
  __shared__ int lab[TT];

  // --- one-time loads -------------------------------------------------------
  half2_t w[64];  // W_hh[t][0..127] as f16 pairs (full row)
  {
    const float4* wr = (const float4*)(Whh + (size_t)t * HH);
#pragma unroll
    for (int i = 0; i < 32; ++i) {
      float4 v = wr[i];
      half2_t p0, p1;
      p0[0] = (_Float16)v.x; p0[1] = (_Float16)v.y;
      p1[0] = (_Float16)v.z; p1[1] = (_Float16)v.w;
      w[2 * i] = p0; w[2 * i + 1] = p1;
    }
  }
  // et[a] = exp(trans[g*32+2a][j]), exp(trans[g*32+2a+1][j])
  half2_t et[16];
#pragma unroll
  for (int a = 0; a < 16; ++a) {
    float e0 = __expf(trans[(g * 32 + 2 * a) * HH + j]);
    float e1 = __expf(trans[(g * 32 + 2 * a + 1) * HH + j]);
    half2_t h2; h2[0] = (_Float16)e0; h2[1] = (_Float16)e1;
    et[a] = h2;
  }
  lab[t] = labels[b * TT + t];
  if (t < HH) { h_lds[t] = (_Float16)0.f; E_lds[t] = (_Float16)0.f; }

  // wave-0 persistent state (units 2t, 2t+1)
  float tr0x = 0.f, tr0y = 0.f, tr127x = 0.f, tr127y = 0.f;
  if (t < 64) {
    float2 v0 = *(const float2*)(trans + 2 * t);
    float2 v1 = *(const float2*)(trans + 127 * HH + 2 * t);
    tr0x = v0.x; tr0y = v0.y; tr127x = v1.x; tr127y = v1.y;
  }
  float c0 = 0.f, c1 = 0.f, preA = 0.f, preB = 0.f, mused = 0.f, emit = 0.f;

  const float* pcb = precomp + (size_t)b * TT * G4 + t;
  float cbuf[8], nbuf[8];
#pragma unroll
  for (int k = 0; k < 8; ++k) cbuf[k] = pcb[(size_t)k * G4];
  __syncthreads();

#pragma unroll 1
  for (int base = 0; base < TT; base += 8) {
    const bool more = (base + 8 < TT);
    if (more) {
#pragma unroll
      for (int k = 0; k < 8; ++k) nbuf[k] = pcb[(size_t)(base + 8 + k) * G4];
    }
#pragma unroll
    for (int k = 0; k < 8; ++k) {
      const int step = base + k;
      const float cur = cbuf[k];
      // --- phase 1: gate matvec (full K) + CRF quarter dot -----------------
      float a0 = 0.f, a1 = 0.f, a2 = 0.f, a3 = 0.f;
      const float4* hv4 = (const float4*)h_lds;
#pragma unroll
      for (int kc = 0; kc < 16; ++kc) {
        float4 hb = hv4[kc];
        a0 = fdot2f(w[4 * kc + 0], BC(hb.x), a0);
        a1 = fdot2f(w[4 * kc + 1], BC(hb.y), a1);
        a2 = fdot2f(w[4 * kc + 2], BC(hb.z), a2);
        a3 = fdot2f(w[4 * kc + 3], BC(hb.w), a3);
      }
      float s0 = 0.f, s1 = 0.f;
      const float4* ev4 = (const float4*)E_lds + g * 4;
#pragma unroll
      for (int ec = 0; ec < 4; ++ec) {
        float4 eb = ev4[ec];
        s0 = fdot2f(et[4 * ec + 0], BC(eb.x), s0);
        s1 = fdot2f(et[4 * ec + 1], BC(eb.y), s1);
        s0 = fdot2f(et[4 * ec + 2], BC(eb.z), s0);
        s1 = fdot2f(et[4 * ec + 3], BC(eb.w), s1);
      }
      const float gate = cur + ((a0 + a1) + (a2 + a3));
      // branchless activation: sigmoid for i,f,o; tanh for g (g==2)
      const bool isg = (g == 2);
      const float yy = isg ? (-2.f * fabsf(gate)) : (-gate);
      const float exv = __expf(yy);
      const float num = isg ? (1.f - exv) : 1.f;
      float av = num * rcp_(1.f + exv);
      av = isg ? copysignf(av, gate) : av;
      act2[j * 4 + g] = av;
      Spart2[j * 4 + g] = s0 + s1;
      __syncthreads();  // A
      // --- phase 3 (wave 0): cell, softmax, CRF, state writes --------------
      if (t < 64) {
        const float4* av4 = (const float4*)act2;
        float4 A0 = av4[2 * t], A1 = av4[2 * t + 1];       // i,f,g,o
        const float4* sv4 = (const float4*)Spart2;
        float4 S0v = sv4[2 * t], S1v = sv4[2 * t + 1];     // 4 K-quarters
        c0 = A0.y * c0 + A0.x * A0.z;
        c1 = A1.y * c1 + A1.x * A1.z;
        const float h0 = A0.w * tanh_(c0), h1 = A1.w * tanh_(c1);
        const float e0 = __expf(h0), e1 = __expf(h1);  // |h|<1: no max-sub
        const float denom = wave_sum64_bcast(e0 + e1);
        const float rinv = rcp_(denom);
        const float p0 = e0 * rinv, p1 = e1 * rinv;
        const float Sa = (S0v.x + S0v.y) + (S0v.z + S0v.w);
        const float Sb = (S1v.x + S1v.y) + (S1v.z + S1v.w);
        const float lgSa = __logf(Sa), lgSb = __logf(Sb);
        const float lgS0 = readlane_f(lgSa, 0);      // unit 0's log S
        const int lb = lab[step];
        const float Mnext = (step == 0) ? 0.f : (mused + lgS0);
        preA = p0 + ((step == 0) ? tr0x : (mused + lgSa));
        preB = p1 + ((step == 0) ? tr0y : (mused + lgSb));
        if (2 * t == lb) emit += p0;
        if (2 * t + 1 == lb) emit += p1;
        half2_t Eh;
        Eh[0] = (_Float16)__expf(preA - Mnext);  // bounded ~[0.37, 7.4]
        Eh[1] = (_Float16)__expf(preB - Mnext);
        *(half2_t*)&E_lds[2 * t] = Eh;
        half2_t Hh;
        Hh[0] = (_Float16)h0; Hh[1] = (_Float16)h1;
        *(half2_t*)&h_lds[2 * t] = Hh;
        mused = Mnext;
      }
      __syncthreads();  // C
    }
    if (more) {
#pragma unroll
      for (int k = 0; k < 8; ++k) cbuf[k] = nbuf[k];
    }
  }
  // --- epilogue (wave 0): Ps = LSE(pre + trans[127]); out_b = Ps - emit ----
  if (t < 64) {
    float v0 = preA + tr127x, v1 = preB + tr127y;
    float m = fmaxf(v0, v1);
#pragma unroll
    for (int s = 1; s <= 32; s <<= 1) m = fmaxf(m, __shfl_xor(m, s));
    float ex = __expf(v0 - m) + __expf(v1 - m);
    float em = emit;
#pragma unroll
    for (int s = 1; s <= 32; s <<= 1) {
      ex += __shfl_xor(ex, s);
      em += __shfl_xor(em, s);
    }
    if (t == 0) out_b[b] = m + __logf(ex) - em;
  }
}

// ---------------------------------------------------------------------------
// Kernel D: total = sum_b out_b[b] - sum_{b,t<511} trans[l_t][l_{t+1}]
// ---------------------------------------------------------------------------
__global__ __launch_bounds__(512) void finalize_kernel(
    const float* __restrict__ trans, const int* __restrict__ labels,
    const float* __restrict__ out_b, float* __restrict__ d_out) {
  const int t = threadIdx.x;
  float a = 0.f;
  if (t < TT - 1) {
    for (int b = 0; b < BB; ++b) {
      const int l0 = labels[b * TT + t];
      const int l1 = labels[b * TT + t + 1];
      a += trans[l0 * HH + l1];
    }
  }
  float x = ((t < BB) ? out_b[t] : 0.f) - a;
  __shared__ float red[8];
#pragma unroll
  for (int s = 32; s >= 1; s >>= 1) x += __shfl_xor(x, s);
  if ((t & 63) == 0) red[t >> 6] = x;
  __syncthreads();
  if (t == 0) {
    float s = 0.f;
#pragma unroll
    for (int i = 0; i < 8; ++i) s += red[i];
    d_out[0] = s;
  }
}

// ---------------------------------------------------------------------------
extern "C" void kernel_launch(void* const* d_in, const int* in_sizes, int n_in,
                              void* d_out, int out_size, void* d_ws, size_t ws_size,
                              hipStream_t stream) {
  const float* inputs = (const float*)d_in[0];      // (64,512,256) f32
  const int* labels = (const int*)d_in[1];          // (64,512) i32
  const float* W_ih = (const float*)d_in[2];        // (512,256) f32
  const float* W_hh = (const float*)d_in[3];        // (512,128) f32
  const float* b_ih = (const float*)d_in[4];        // (512,) f32
  const float* b_hh = (const float*)d_in[5];        // (512,) f32
  const float* transition = (const float*)d_in[6];  // (128,128) f32

  char* ws = (char*)d_ws;
  float* precomp = (float*)ws;                           // 64 MiB
  float* trans = (float*)(ws + 67108864);                // 64 KiB
  _Float16* W16 = (_Float16*)(ws + 67108864 + 65536);    // 256 KiB
  float* out_b = (float*)(ws + 67108864 + 65536 + 262144);

  prep_kernel<<<256, 128, 0, stream>>>(transition, W_ih, trans, W16);
  gemm_in<<<dim3(512, 2), 256, 0, stream>>>(inputs, W16, b_ih, b_hh, precomp);
  lstm_crf<<<64, 512, 0, stream>>>(precomp, W_hh, trans, labels, out_b);
  finalize_kernel<<<1, 512, 0, stream>>>(trans, labels, out_b, (float*)d_out);
}